// Round 2
// baseline (444.148 us; speedup 1.0000x reference)
//
#include <hip/hip_runtime.h>

// KernelNorm2d: B=16, C=64, H=W=256, k=2, s=2, pad=0, eps=1e-5, fp32.
// stride==kernel -> out[b,c,h,w] = (x-mu)/sqrt(var+eps), stats over the
// 256 elements {all 64 channels} x {2x2 spatial window}.
//
// Block = (batch b, window-row i): 64ch x 2rows x 256cols = 128 KB held in
// registers across 1024 threads (8 float4 each). Every wave-load/store is a
// full 1-KB contiguous image row; each channel is a 2-KB contiguous run
// (rows 2i, 2i+1) -> DRAM row-buffer friendly, unlike the previous 256-B
// segments at 256-KB power-of-2 strides.

#define CC 64
#define HH 256
#define WW 256

// Native clang vector type: __builtin_nontemporal_store requires it
// (HIP's float4 is a HIP_vector_type class and is rejected).
typedef float floatx4 __attribute__((ext_vector_type(4)));

__global__ __launch_bounds__(1024)
void knorm2d_kernel(const float* __restrict__ x, float* __restrict__ out) {
    const int t    = threadIdx.x;
    const int b    = blockIdx.x >> 7;    // 128 blocks per batch
    const int i    = blockIdx.x & 127;   // window-row (image rows 2i, 2i+1)
    const int wave = t >> 6;             // 0..15
    const int l    = t & 63;             // lane: columns 4l..4l+3
    const int h    = wave & 1;           // row within window
    const int w2   = wave >> 1;          // channel sub-index 0..7

    // float4 for iteration k lives at (c = k*8 + w2, row 2i+h, cols 4l..4l+3).
    // A wave's 64 lanes cover one full 1-KB row contiguously.
    const size_t base = (size_t)b * (CC * HH * WW)
                      + (size_t)w2 * (HH * WW)
                      + (size_t)(2 * i + h) * WW
                      + (size_t)(4 * l);

    floatx4 data[8];
    float sum0 = 0.f, sum1 = 0.f, ssq0 = 0.f, ssq1 = 0.f;

    #pragma unroll
    for (int k = 0; k < 8; ++k) {
        const size_t off = base + (size_t)k * (8 * HH * WW);
        const floatx4 v = *reinterpret_cast<const floatx4*>(x + off);
        data[k] = v;
        sum0 += v.x + v.y;   ssq0 += v.x * v.x + v.y * v.y;
        sum1 += v.z + v.w;   ssq1 += v.z * v.z + v.w * v.w;
    }

    // Lane l of every wave holds partials for windows 2l (x,y) and 2l+1 (z,w).
    // Reduce the 16 waves through LDS.
    __shared__ float part[16][64][4];   // [wave][lane][{s0,q0,s1,q1}]
    __shared__ float stats[128][2];     // [window j][{mu, rsig}]

    part[wave][l][0] = sum0;
    part[wave][l][1] = ssq0;
    part[wave][l][2] = sum1;
    part[wave][l][3] = ssq1;
    __syncthreads();

    if (t < 128) {                      // thread t owns window j = t
        const int lw = t >> 1;          // owning lane
        const int q  = t & 1;           // which half of that lane's pair
        float s = 0.f, s2 = 0.f;
        #pragma unroll
        for (int w = 0; w < 16; ++w) {
            s  += part[w][lw][2 * q];
            s2 += part[w][lw][2 * q + 1];
        }
        const float mu  = s  * (1.0f / 256.0f);
        const float var = s2 * (1.0f / 256.0f) - mu * mu;
        stats[t][0] = mu;
        stats[t][1] = rsqrtf(var + 1e-5f);
    }
    __syncthreads();

    const float mu0 = stats[2 * l][0],     rs0 = stats[2 * l][1];
    const float mu1 = stats[2 * l + 1][0], rs1 = stats[2 * l + 1][1];

    #pragma unroll
    for (int k = 0; k < 8; ++k) {
        const size_t off = base + (size_t)k * (8 * HH * WW);
        const floatx4 v = data[k];
        floatx4 o;
        o.x = (v.x - mu0) * rs0;
        o.y = (v.y - mu0) * rs0;
        o.z = (v.z - mu1) * rs1;
        o.w = (v.w - mu1) * rs1;
        // Output is never re-read: keep it out of L2.
        __builtin_nontemporal_store(o, reinterpret_cast<floatx4*>(out + off));
    }
}

extern "C" void kernel_launch(void* const* d_in, const int* in_sizes, int n_in,
                              void* d_out, int out_size, void* d_ws, size_t ws_size,
                              hipStream_t stream) {
    const float* x = (const float*)d_in[0];
    float* out     = (float*)d_out;
    // 16 batches * 128 window-rows = 2048 blocks of 1024 threads.
    knorm2d_kernel<<<dim3(2048), dim3(1024), 0, stream>>>(x, out);
}